// Round 15
// baseline (1610.271 us; speedup 1.0000x reference)
//
#include <hip/hip_runtime.h>
#include <hip/hip_bf16.h>
#include <cstdint>
#include <cstddef>

#define DEV __device__ __forceinline__

using f32x4 = __attribute__((ext_vector_type(4))) float;
using bfx8  = __attribute__((ext_vector_type(8))) __bf16;
using s16x8 = __attribute__((ext_vector_type(8))) short;

// ---------- helpers ----------
DEV uint16_t f2bf(float f) {
    union { float f; uint32_t u; } x; x.f = f;
    uint32_t r = x.u + 0x7fffu + ((x.u >> 16) & 1u);   // RNE
    return (uint16_t)(r >> 16);
}

DEV float gelu_exact(float v) {
    return 0.5f * v * (1.0f + erff(v * 0.70710678118654752f));
}

DEV f32x4 mfma16(s16x8 a, s16x8 b, f32x4 c) {
    return __builtin_amdgcn_mfma_f32_16x16x32_bf16(
        __builtin_bit_cast(bfx8, a), __builtin_bit_cast(bfx8, b), c, 0, 0, 0);
}

DEV void async_lds16(const void* g, void* l) {
    __builtin_amdgcn_global_load_lds(
        (const __attribute__((address_space(1))) uint32_t*)g,
        (__attribute__((address_space(3))) uint32_t*)l, 16, 0, 0);
}

template<int N> DEV void wait_vm() {
    if constexpr (N == 0)      asm volatile("s_waitcnt vmcnt(0)" ::: "memory");
    else if constexpr (N == 6) asm volatile("s_waitcnt vmcnt(6)" ::: "memory");
    else static_assert(N == 0, "add vmcnt literal");
}
#define SBAR   asm volatile("s_barrier" ::: "memory")
#define LGKM0  asm volatile("s_waitcnt lgkmcnt(0)" ::: "memory")
#define SCHED0 __builtin_amdgcn_sched_barrier(0)

// ---------- LayerNorm: f32 [rows,512] -> bf16 (optional scale/bias), one wave/row ----------
template<int HAS_SB>
__global__ __launch_bounds__(256)
void ln_t(const float* __restrict__ in, const float* __restrict__ sc,
          const float* __restrict__ bi, uint16_t* __restrict__ out)
{
    const int lane = threadIdx.x & 63;
    const size_t row = (size_t)blockIdx.x * 4 + (threadIdx.x >> 6);
    const float* p = in + row * 512 + lane * 8;
    float4 a = *(const float4*)p;
    float4 b4 = *(const float4*)(p + 4);
    float v[8] = {a.x, a.y, a.z, a.w, b4.x, b4.y, b4.z, b4.w};
    float s = 0.f, sq = 0.f;
#pragma unroll
    for (int j = 0; j < 8; ++j) { s += v[j]; sq += v[j] * v[j]; }
#pragma unroll
    for (int o = 1; o < 64; o <<= 1) { s += __shfl_xor(s, o); sq += __shfl_xor(sq, o); }
    const float mean = s * (1.0f / 512.0f);
    const float var  = sq * (1.0f / 512.0f) - mean * mean;
    const float rstd = rsqrtf(var + 1e-5f);
    const int c = lane * 8;
    uint16_t o8[8];
#pragma unroll
    for (int j = 0; j < 8; ++j) {
        float z = (v[j] - mean) * rstd;
        if (HAS_SB) z = z * sc[c + j] + bi[c + j];
        o8[j] = f2bf(z);
    }
    uint4 pk;
    pk.x = (uint32_t)o8[0] | ((uint32_t)o8[1] << 16);
    pk.y = (uint32_t)o8[2] | ((uint32_t)o8[3] << 16);
    pk.z = (uint32_t)o8[4] | ((uint32_t)o8[5] << 16);
    pk.w = (uint32_t)o8[6] | ((uint32_t)o8[7] << 16);
    *reinterpret_cast<uint4*>(out + row * 512 + c) = pk;
}

// ---------- weight transpose-convert: f32 [L][K][N] -> bf16 [L][row0+N][K], opt row-scale ----------
__global__ __launch_bounds__(256)
void wtrans(const float* __restrict__ W, uint16_t* __restrict__ WT, int K, int N,
            size_t lstride, int row0, const float* __restrict__ kscale)
{
    __shared__ float tile[32][33];
    const int l = blockIdx.z;
    const int k0 = blockIdx.x * 32, n0 = blockIdx.y * 32;
    const float* Wl = W + (size_t)l * K * N;
    uint16_t* WTl = WT + (size_t)l * lstride;
    const int tx = threadIdx.x, ty = threadIdx.y;  // (32,8)
#pragma unroll
    for (int j = 0; j < 4; ++j) {
        const int k = k0 + ty + j * 8;
        float w = Wl[(size_t)k * N + n0 + tx];
        if (kscale) w *= kscale[l * K + k];
        tile[ty + j * 8][tx] = w;
    }
    __syncthreads();
#pragma unroll
    for (int j = 0; j < 4; ++j)
        WTl[(size_t)(row0 + n0 + ty + j * 8) * K + k0 + tx] = f2bf(tile[tx][ty + j * 8]);
}

// ---------- bias fold: out[l*1024 + (z?512:0) + n] = sum_k b[l][k] * W[l][k][n] ----------
__global__ __launch_bounds__(256)
void bfold(const float* __restrict__ b, const float* __restrict__ Wq,
           const float* __restrict__ Wk, float* __restrict__ out)
{
    const int n = blockIdx.x * 256 + threadIdx.x;   // grid (2, 6, 2)
    const int l = blockIdx.y, sel = blockIdx.z;
    const float* bb = b + l * 512;
    const float* W = (sel ? Wk : Wq) + (size_t)l * 512 * 512;
    float s = 0.f;
    for (int k = 0; k < 512; ++k) s += bb[k] * W[(size_t)k * 512 + n];
    out[l * 1024 + sel * 512 + n] = s;
}

// ---------- GEMM X: phase-interleaved 3-buffer pipeline (m201-style), 256x128, BK=64 ----------
// Per K-tile T: vmcnt(6) [tile T landed; T+1's 6 loads stay in flight] -> s_barrier ->
// 4 phases {8 ds_read_b128 quadrant || 2 global_load_lds of tile T+2 into buf (T+2)%3
//  (= tile T-1's buffer, fully consumed before this tile's opening barrier -> WAR-safe)
//  -> lgkmcnt(0)+sched_barrier -> setprio(1) 8 MFMA setprio(0) -> s_barrier}.
// Fragment-ordered LDS (proven 0-conflict). 8 waves (4M x 2N), per-wave 64x64.
template<int HAS_BIAS, int DO_GELU>
__global__ __launch_bounds__(512, 1)
void gemmX(const uint16_t* __restrict__ A, const uint16_t* __restrict__ BT,
           const float* __restrict__ bias, uint16_t* __restrict__ outp,
           int M, int N, int K)
{
    constexpr int BM = 256, BN = 128;
    __shared__ uint16_t As3[3][2048 * 8];   // [sub 8][row 256][8]  32 KB/buf
    __shared__ uint16_t Bs3[3][1024 * 8];   // [sub 8][row 128][8]  16 KB/buf
    const int tid = threadIdx.x, lane = tid & 63;
    const int w = tid >> 6, wr = w >> 1, wc = w & 1;
    const int kg = lane >> 4, lr = lane & 15;
    // 2D-rectangle XCD swizzle (nbm%2==0, nbn%4==0 for all call sites)
    const int nbn = N / BN, nbm = M / BM;
    const int rect_m = nbm >> 1, rect_n = nbn >> 2;
    const int xcd = blockIdx.x & 7, cc = blockIdx.x >> 3;
    const int bm = (xcd >> 2) * rect_m + cc / rect_n;
    const int bn = (xcd & 3) * rect_n + cc % rect_n;
    const size_t m0 = (size_t)bm * BM, n0 = (size_t)bn * BN;
    const int nt = K / 64;

    auto stage2 = [&](int buf, int tile, int jb) {
        const int k0 = tile * 64;
#pragma unroll
        for (int j = 0; j < 2; ++j) {
            const int s = (jb + j) * 512 + tid;
            if (s < 2048) {
                const int sub = s >> 8, row = s & 255;
                async_lds16(A + (m0 + row) * K + k0 + sub * 8, &As3[buf][s * 8]);
            } else {
                const int s2 = s - 2048;
                const int sub = s2 >> 7, row = s2 & 127;
                async_lds16(BT + (n0 + row) * K + k0 + sub * 8, &Bs3[buf][s2 * 8]);
            }
        }
    };

    f32x4 acc[4][4] = {};
    stage2(0, 0, 0); stage2(0, 0, 2); stage2(0, 0, 4);   // tile 0: 6 loads
    stage2(1, 1, 0); stage2(1, 1, 2); stage2(1, 1, 4);   // tile 1: 6 loads
    for (int T = 0; T < nt; ++T) {
        if (T + 1 < nt) wait_vm<6>(); else wait_vm<0>();
        SBAR;                                  // all waves' tile-T loads landed
        const int cb = T % 3, pb = (T + 2) % 3;
        const bool pf = (T + 2 < nt);
#pragma unroll
        for (int q = 0; q < 4; ++q) {
            const int mh = q >> 1, nh = q & 1;
            // quadrant ds-reads (fragment-ordered, conflict-free)
            s16x8 af[2][2], bg[2][2];
#pragma unroll
            for (int ks = 0; ks < 2; ++ks)
#pragma unroll
                for (int i = 0; i < 2; ++i) {
                    af[ks][i] = *(const s16x8*)&As3[cb][((ks * 4 + kg) * 256 + wr * 64 + (mh * 2 + i) * 16 + lr) * 8];
                    bg[ks][i] = *(const s16x8*)&Bs3[cb][((ks * 4 + kg) * 128 + wc * 64 + (nh * 2 + i) * 16 + lr) * 8];
                }
            // interleaved prefetch: 2 loads of tile T+2 at phases 0..2
            if (pf && q < 3) stage2(pb, T + 2, q * 2);
            LGKM0; SCHED0;                      // ds_reads landed (rule #18 fence)
            __builtin_amdgcn_s_setprio(1);
#pragma unroll
            for (int ks = 0; ks < 2; ++ks)
#pragma unroll
                for (int i = 0; i < 2; ++i)
#pragma unroll
                    for (int j = 0; j < 2; ++j)
                        acc[mh * 2 + i][nh * 2 + j] =
                            mfma16(af[ks][i], bg[ks][j], acc[mh * 2 + i][nh * 2 + j]);
            __builtin_amdgcn_s_setprio(0);
            SBAR;                               // phase-lock waves (role split)
        }
    }
    // epilogue: bias (+gelu), bf16 out
#pragma unroll
    for (int i = 0; i < 4; ++i) {
        const size_t rbase = m0 + wr * 64 + i * 16 + kg * 4;
#pragma unroll
        for (int j = 0; j < 4; ++j) {
            const size_t col = n0 + wc * 64 + j * 16 + lr;
            const float bval = HAS_BIAS ? bias[col] : 0.0f;
#pragma unroll
            for (int r = 0; r < 4; ++r) {
                float v = acc[i][j][r] + bval;
                if (DO_GELU) v = gelu_exact(v);
                outp[(rbase + r) * (size_t)N + col] = f2bf(v);
            }
        }
    }
}

// ---------- GEMM v9b: m97-geometry, 4 waves, template BK (32/64), single-buffer ----------
template<int BM, int BN, int BK, int MINW,
         int HAS_BIAS, int HAS_RESID, int DO_GELU, int OUT_BF16, int OUT_VT>
__global__ __launch_bounds__(256, MINW)
void gemm9(const uint16_t* __restrict__ A, const uint16_t* __restrict__ BT,
           const float* __restrict__ bias, const float* __restrict__ resid,
           void* __restrict__ outp, uint16_t* __restrict__ vt,
           int M, int N, int K)
{
    constexpr int WM = BM / 2, WN = BN / 2;
    constexpr int FM = WM / 16, FN = WN / 16;
    constexpr int NSUB = BK / 8;
    constexpr int ASLOTS = NSUB * BM, BSLOTS = NSUB * BN, TOT = ASLOTS + BSLOTS;
    constexpr int S = TOT / 256;
    static_assert(TOT % 256 == 0, "slot count");
    __shared__ uint16_t As[ASLOTS * 8];
    __shared__ uint16_t Bs[BSLOTS * 8];
    const int tid = threadIdx.x, lane = tid & 63;
    const int w = tid >> 6, wr = w >> 1, wc = w & 1;
    const int kg = lane >> 4, lr = lane & 15;
    const int nbn = N / BN, nbm = M / BM;
    const int rect_m = nbm >> 1, rect_n = (nbn >= 4) ? (nbn >> 2) : 1;
    const int xcd = blockIdx.x & 7, c = blockIdx.x >> 3;
    int bm, bn;
    if (nbn >= 4) {
        bm = (xcd >> 2) * rect_m + c / rect_n;
        bn = (xcd & 3) * rect_n + c % rect_n;
    } else {
        const int idx = xcd * ((nbm * nbn) >> 3) + c;
        bm = idx / nbn; bn = idx % nbn;
    }
    const size_t m0 = (size_t)bm * BM;
    const size_t n0 = (size_t)bn * BN;

    f32x4 acc[FM][FN] = {};
    for (int k0 = 0; k0 < K; k0 += BK) {
#pragma unroll
        for (int j = 0; j < S; ++j) {
            const int s = j * 256 + tid;
            if (s < ASLOTS) {
                const int sub = s / BM, row = s % BM;
                async_lds16(A + (m0 + row) * K + k0 + sub * 8, &As[s * 8]);
            } else {
                const int s2 = s - ASLOTS;
                const int sub = s2 / BN, row = s2 % BN;
                async_lds16(BT + (n0 + row) * K + k0 + sub * 8, &Bs[s2 * 8]);
            }
        }
        __syncthreads();
#pragma unroll
        for (int ks = 0; ks < BK / 32; ++ks) {
            s16x8 af[FM], bf[FN];
#pragma unroll
            for (int i = 0; i < FM; ++i)
                af[i] = *(const s16x8*)&As[((ks * 4 + kg) * BM + wr * WM + i * 16 + lr) * 8];
#pragma unroll
            for (int j = 0; j < FN; ++j)
                bf[j] = *(const s16x8*)&Bs[((ks * 4 + kg) * BN + wc * WN + j * 16 + lr) * 8];
#pragma unroll
            for (int i = 0; i < FM; ++i)
#pragma unroll
                for (int j = 0; j < FN; ++j)
                    acc[i][j] = mfma16(af[i], bf[j], acc[i][j]);
        }
        __syncthreads();
    }
    if (OUT_VT == 1 || (OUT_VT == 2 && n0 >= 1024)) {
#pragma unroll
        for (int i = 0; i < FM; ++i) {
            const size_t rbase = m0 + wr * WM + i * 16 + kg * 4;
            const int b = (int)(rbase >> 10), nloc = (int)(rbase & 1023);
#pragma unroll
            for (int j = 0; j < FN; ++j) {
                const int col = (int)n0 + wc * WN + j * 16 + lr;
                const int c2 = (OUT_VT == 2) ? col - 1024 : col;
                const float bval = HAS_BIAS ? bias[c2] : 0.0f;
                const int h = c2 >> 6, d = c2 & 63;
                ushort4 pk;
                pk.x = f2bf(acc[i][j][0] + bval);
                pk.y = f2bf(acc[i][j][1] + bval);
                pk.z = f2bf(acc[i][j][2] + bval);
                pk.w = f2bf(acc[i][j][3] + bval);
                *(ushort4*)&vt[((size_t)(b * 8 + h) * 64 + d) * 1024 + nloc] = pk;
            }
        }
        return;
    }
#pragma unroll
    for (int i = 0; i < FM; ++i) {
        const size_t rbase = m0 + wr * WM + i * 16 + kg * 4;
#pragma unroll
        for (int j = 0; j < FN; ++j) {
            const size_t col = n0 + wc * WN + j * 16 + lr;
            const float bval = HAS_BIAS ? bias[col] : 0.0f;
#pragma unroll
            for (int r = 0; r < 4; ++r) {
                const size_t row = rbase + r;
                float v = acc[i][j][r] + bval;
                if (DO_GELU)  v = gelu_exact(v);
                if (HAS_RESID) v += resid[row * (size_t)N + col];
                if (OUT_BF16) ((uint16_t*)outp)[row * (size_t)N + col] = f2bf(v);
                else          ((float*)outp)[row * (size_t)N + col] = v;
            }
        }
    }
}

// ---------- flash attention: no-max softmax, fragment-ordered LDS, QBLK=64, 4 waves ----------
__global__ __launch_bounds__(256)
void attn_flash(const uint16_t* __restrict__ Qb, const uint16_t* __restrict__ Kb,
                const uint16_t* __restrict__ Vt, uint16_t* __restrict__ Ob,
                int qstride, int kstride, int qoff, int koff)
{
    __shared__ uint16_t Ks[2][4096];
    __shared__ uint16_t Vs[2][4096];
    __shared__ uint16_t Pb[4][1024];
    const int tid = threadIdx.x, lane = tid & 63, w = tid >> 6;
    const int kg = lane >> 4, lr = lane & 15;
    const int bh = blockIdx.y, b = bh >> 3, h = bh & 7;
    const int q0 = blockIdx.x * 64;
    const float CEXP = 0.125f * 1.44269504f;

    s16x8 aq0, aq1;
    {
        const size_t qrow = (size_t)b * 1024 + q0 + w * 16 + lr;
        const uint16_t* qp = Qb + qrow * qstride + qoff + h * 64 + kg * 8;
        aq0 = *(const s16x8*)qp;
        aq1 = *(const s16x8*)(qp + 32);
    }
    const uint16_t* kbase = Kb + (size_t)b * 1024 * kstride + koff + h * 64;
    const uint16_t* vbase = Vt + (size_t)bh * 65536;

    float l_r[4] = {0.f, 0.f, 0.f, 0.f};
    f32x4 acc[4] = {};

    auto stage = [&](int buf, int kv0) {
#pragma unroll
        for (int j = 0; j < 2; ++j) {
            const int s = j * 256 + tid;
            const int sub = s >> 6, row = s & 63;
            async_lds16(kbase + (size_t)(kv0 + row) * kstride + sub * 8, &Ks[buf][s * 8]);
            async_lds16(vbase + (size_t)row * 1024 + kv0 + sub * 8,      &Vs[buf][s * 8]);
        }
    };

    stage(0, 0);
    __syncthreads();
    int cur = 0;
    for (int t = 0; t < 16; ++t) {
        if (t < 15) stage(cur ^ 1, (t + 1) * 64);
        f32x4 s4[4];
        __builtin_amdgcn_s_setprio(1);
#pragma unroll
        for (int ni = 0; ni < 4; ++ni) {
            s16x8 bk0 = *(const s16x8*)&Ks[cur][(kg * 64 + ni * 16 + lr) * 8];
            s16x8 bk1 = *(const s16x8*)&Ks[cur][((4 + kg) * 64 + ni * 16 + lr) * 8];
            f32x4 z = {};
            z = mfma16(aq0, bk0, z);
            z = mfma16(aq1, bk1, z);
            s4[ni] = z;
        }
        __builtin_amdgcn_s_setprio(0);
#pragma unroll
        for (int ni = 0; ni < 4; ++ni) {
            const int slotb = (ni * 2 + (lr >> 3)) * 16 + kg * 4;
#pragma unroll
            for (int r = 0; r < 4; ++r) {
                const float pe = __builtin_amdgcn_exp2f(s4[ni][r] * CEXP);
                l_r[r] += pe;
                Pb[w][(slotb + r) * 8 + (lr & 7)] = f2bf(pe);
            }
        }
        s16x8 ap0 = *(const s16x8*)&Pb[w][(kg * 16 + lr) * 8];
        s16x8 ap1 = *(const s16x8*)&Pb[w][((4 + kg) * 16 + lr) * 8];
        __builtin_amdgcn_s_setprio(1);
#pragma unroll
        for (int ni = 0; ni < 4; ++ni) {
            s16x8 bv0 = *(const s16x8*)&Vs[cur][(kg * 64 + ni * 16 + lr) * 8];
            s16x8 bv1 = *(const s16x8*)&Vs[cur][((4 + kg) * 64 + ni * 16 + lr) * 8];
            acc[ni] = mfma16(ap0, bv0, acc[ni]);
            acc[ni] = mfma16(ap1, bv1, acc[ni]);
        }
        __builtin_amdgcn_s_setprio(0);
        __syncthreads();
        cur ^= 1;
    }
    float linv[4];
#pragma unroll
    for (int r = 0; r < 4; ++r) {
        float l = l_r[r];
        l += __shfl_xor(l, 1); l += __shfl_xor(l, 2);
        l += __shfl_xor(l, 4); l += __shfl_xor(l, 8);
        linv[r] = 1.0f / l;
    }
#pragma unroll
    for (int ni = 0; ni < 4; ++ni)
#pragma unroll
        for (int r = 0; r < 4; ++r) {
            const float v = acc[ni][r] * linv[r];
            const size_t row = (size_t)b * 1024 + q0 + w * 16 + kg * 4 + r;
            Ob[row * 512 + h * 64 + ni * 16 + lr] = f2bf(v);
        }
}

// ---------- host ----------
extern "C" void kernel_launch(void* const* d_in, const int* in_sizes, int n_in,
                              void* d_out, int out_size, void* d_ws, size_t ws_size,
                              hipStream_t stream)
{
    (void)in_sizes; (void)n_in; (void)out_size; (void)ws_size;
    const float* g     = (const float*)d_in[0];
    const float* x0    = (const float*)d_in[1];
    const float* ln1_s = (const float*)d_in[2];
    const float* ln1_b = (const float*)d_in[3];
    const float* Wqkv  = (const float*)d_in[4];
    const float* Wo_sa = (const float*)d_in[5];
    const float* bo_sa = (const float*)d_in[6];
    const float* lng_s = (const float*)d_in[7];
    const float* lng_b = (const float*)d_in[8];
    const float* lnx_s = (const float*)d_in[9];
    const float* lnx_b = (const float*)d_in[10];
    const float* Wq    = (const float*)d_in[11];
    const float* Wk    = (const float*)d_in[12];
    const float* Wv    = (const float*)d_in[13];
    const float* bv    = (const float*)d_in[14];
    const float* Wo_ca = (const float*)d_in[15];
    const float* bo_ca = (const float*)d_in[16];
    const float* lnf_s = (const float*)d_in[17];
    const float* lnf_b = (const float*)d_in[18];
    const float* W1    = (const float*)d_in[19];
    const float* b1    = (const float*)d_in[20];
    const float* W2    = (const float*)d_in[21];
    const float* b2    = (const float*)d_in[22];

    float* x = (float*)d_out;  // running residual stream (f32)

    char* p = (char*)d_ws;
    auto carve = [&](size_t n) { char* r = p; p += (n + 255) & ~(size_t)255; return r; };
    uint16_t* WqkT  = (uint16_t*)carve(6ull * 1024 * 512 * 2);
    uint16_t* WvT   = (uint16_t*)carve(6ull * 512 * 512 * 2);
    uint16_t* WocaT = (uint16_t*)carve(6ull * 512 * 512 * 2);
    uint16_t* WqkvT = (uint16_t*)carve(6ull * 1536 * 512 * 2);
    uint16_t* WosaT = (uint16_t*)carve(6ull * 512 * 512 * 2);
    uint16_t* W1T   = (uint16_t*)carve(6ull * 2048 * 512 * 2);
    uint16_t* W2T   = (uint16_t*)carve(6ull * 512 * 2048 * 2);
    float*    bqk   = (float*)carve(6144ull * 4);
    uint16_t* zg    = (uint16_t*)carve(4096ull * 512 * 2);
    uint16_t* qkall = (uint16_t*)carve(4096ull * 6144 * 2);
    uint16_t* xn    = (uint16_t*)carve(4096ull * 512 * 2);
    uint16_t* qkvu  = (uint16_t*)carve(4096ull * 1536 * 2);
    uint16_t* vt    = (uint16_t*)carve(32ull * 64 * 1024 * 2);
    uint16_t* ab    = (uint16_t*)carve(4096ull * 512 * 2);
    uint16_t* hb    = (uint16_t*)carve(4096ull * 2048 * 2);

    // ---- prep ----
    dim3 tb(32, 8);
    wtrans<<<dim3(16, 16, 6), tb, 0, stream>>>(Wq,    WqkT,  512, 512,  1024ull * 512, 0,   lng_s);
    wtrans<<<dim3(16, 16, 6), tb, 0, stream>>>(Wk,    WqkT,  512, 512,  1024ull * 512, 512, lng_s);
    wtrans<<<dim3(16, 16, 6), tb, 0, stream>>>(Wv,    WvT,   512, 512,  512ull * 512, 0, nullptr);
    wtrans<<<dim3(16, 16, 6), tb, 0, stream>>>(Wo_ca, WocaT, 512, 512,  512ull * 512, 0, nullptr);
    wtrans<<<dim3(16, 48, 6), tb, 0, stream>>>(Wqkv,  WqkvT, 512, 1536, 1536ull * 512, 0, nullptr);
    wtrans<<<dim3(16, 16, 6), tb, 0, stream>>>(Wo_sa, WosaT, 512, 512,  512ull * 512, 0, nullptr);
    wtrans<<<dim3(16, 64, 6), tb, 0, stream>>>(W1,    W1T,   512, 2048, 2048ull * 512, 0, nullptr);
    wtrans<<<dim3(64, 16, 6), tb, 0, stream>>>(W2,    W2T,   2048, 512, 2048ull * 512, 0, nullptr);
    bfold<<<dim3(2, 6, 2), 256, 0, stream>>>(lng_b, Wq, Wk, bqk);

    hipMemcpyAsync(x, x0, 4096ull * 512 * 4, hipMemcpyDeviceToDevice, stream);

    // ---- hoisted Q/K for all layers: phase-interleaved pipeline (grid 16x48=768) ----
    ln_t<0><<<1024, 256, 0, stream>>>(g, nullptr, nullptr, zg);
    ln_t<1><<<1024, 256, 0, stream>>>(x, lnx_s, lnx_b, xn);
    gemmX<1, 0><<<768, 512, 0, stream>>>(zg, WqkT, bqk, qkall, 4096, 6144, 512);

    const dim3 ga(16, 32);

    for (int l = 0; l < 6; ++l) {
        const size_t o512 = (size_t)l * 512, oW = (size_t)l * 512 * 512;
        const size_t oW1 = (size_t)l * 2048 * 512, oWqkv = (size_t)l * 1536 * 512;
        const size_t o2048 = (size_t)l * 2048;

        // ---- relational cross attention (Q,K precomputed) ----
        gemm9<64, 64, 64, 5, 1, 0, 0, 0, 1><<<512, 256, 0, stream>>>(
            xn, WvT + oW, bv + o512, nullptr, nullptr, vt, 4096, 512, 512);
        attn_flash<<<ga, 256, 0, stream>>>(qkall, qkall, vt, ab, 6144, 6144,
                                           l * 1024, l * 1024 + 512);
        gemm9<64, 64, 64, 5, 1, 1, 0, 0, 0><<<512, 256, 0, stream>>>(
            ab, WocaT + oW, bo_ca + o512, x, x, nullptr, 4096, 512, 512);

        // ---- feed-forward 1 ----
        ln_t<1><<<1024, 256, 0, stream>>>(x, lnf_s + o512, lnf_b + o512, xn);
        gemmX<1, 1><<<256, 512, 0, stream>>>(xn, W1T + oW1, b1 + o2048, hb, 4096, 2048, 512);
        gemm9<64, 64, 64, 5, 1, 1, 0, 0, 0><<<512, 256, 0, stream>>>(
            hb, W2T + oW1, b2 + o512, x, x, nullptr, 4096, 512, 2048);
        ln_t<1><<<1024, 256, 0, stream>>>(x, ln1_s + o512, ln1_b + o512, xn);

        // ---- pre-norm self attention ----
        gemm9<128, 128, 32, 3, 0, 0, 0, 1, 2><<<384, 256, 0, stream>>>(
            xn, WqkvT + oWqkv, nullptr, nullptr, qkvu, vt, 4096, 1536, 512);
        attn_flash<<<ga, 256, 0, stream>>>(qkvu, qkvu, vt, ab, 1536, 1536, 0, 512);
        gemm9<64, 64, 64, 5, 1, 1, 0, 0, 0><<<512, 256, 0, stream>>>(
            ab, WosaT + oW, bo_sa + o512, x, x, nullptr, 4096, 512, 512);

        // ---- feed-forward 2 ----
        ln_t<1><<<1024, 256, 0, stream>>>(x, lnf_s + o512, lnf_b + o512, xn);
        gemmX<1, 1><<<256, 512, 0, stream>>>(xn, W1T + oW1, b1 + o2048, hb, 4096, 2048, 512);
        gemm9<64, 64, 64, 5, 1, 1, 0, 0, 0><<<512, 256, 0, stream>>>(
            hb, W2T + oW1, b2 + o512, x, x, nullptr, 4096, 512, 2048);
        if (l < 5)
            ln_t<1><<<1024, 256, 0, stream>>>(x, lnx_s + o512 + 512, lnx_b + o512 + 512, xn);
    }
}

// Round 16
// 1584.831 us; speedup vs baseline: 1.0161x; 1.0161x over previous
//
#include <hip/hip_runtime.h>
#include <hip/hip_bf16.h>
#include <cstdint>
#include <cstddef>

#define DEV __device__ __forceinline__

using f32x4 = __attribute__((ext_vector_type(4))) float;
using bfx8  = __attribute__((ext_vector_type(8))) __bf16;
using s16x8 = __attribute__((ext_vector_type(8))) short;

// ---------- helpers ----------
DEV uint16_t f2bf(float f) {
    union { float f; uint32_t u; } x; x.f = f;
    uint32_t r = x.u + 0x7fffu + ((x.u >> 16) & 1u);   // RNE
    return (uint16_t)(r >> 16);
}

DEV float gelu_exact(float v) {
    return 0.5f * v * (1.0f + erff(v * 0.70710678118654752f));
}

DEV f32x4 mfma16(s16x8 a, s16x8 b, f32x4 c) {
    return __builtin_amdgcn_mfma_f32_16x16x32_bf16(
        __builtin_bit_cast(bfx8, a), __builtin_bit_cast(bfx8, b), c, 0, 0, 0);
}

DEV void async_lds16(const void* g, void* l) {
    __builtin_amdgcn_global_load_lds(
        (const __attribute__((address_space(1))) uint32_t*)g,
        (__attribute__((address_space(3))) uint32_t*)l, 16, 0, 0);
}

template<int N> DEV void wait_vmcnt() {
    if constexpr (N == 0)      asm volatile("s_waitcnt vmcnt(0)" ::: "memory");
    else if constexpr (N == 4) asm volatile("s_waitcnt vmcnt(4)" ::: "memory");
    else static_assert(N == 0 || N == 4, "add vmcnt literal");
}
#define SBAR      asm volatile("s_barrier" ::: "memory")
#define LGKM0     asm volatile("s_waitcnt lgkmcnt(0)" ::: "memory")
#define SCHED0    __builtin_amdgcn_sched_barrier(0)

// ---------- LayerNorm: f32 [rows,512] -> bf16 (optional scale/bias), one wave/row ----------
template<int HAS_SB>
__global__ __launch_bounds__(256)
void ln_t(const float* __restrict__ in, const float* __restrict__ sc,
          const float* __restrict__ bi, uint16_t* __restrict__ out)
{
    const int lane = threadIdx.x & 63;
    const size_t row = (size_t)blockIdx.x * 4 + (threadIdx.x >> 6);
    const float* p = in + row * 512 + lane * 8;
    float4 a = *(const float4*)p;
    float4 b4 = *(const float4*)(p + 4);
    float v[8] = {a.x, a.y, a.z, a.w, b4.x, b4.y, b4.z, b4.w};
    float s = 0.f, sq = 0.f;
#pragma unroll
    for (int j = 0; j < 8; ++j) { s += v[j]; sq += v[j] * v[j]; }
#pragma unroll
    for (int o = 1; o < 64; o <<= 1) { s += __shfl_xor(s, o); sq += __shfl_xor(sq, o); }
    const float mean = s * (1.0f / 512.0f);
    const float var  = sq * (1.0f / 512.0f) - mean * mean;
    const float rstd = rsqrtf(var + 1e-5f);
    const int c = lane * 8;
    uint16_t o8[8];
#pragma unroll
    for (int j = 0; j < 8; ++j) {
        float z = (v[j] - mean) * rstd;
        if (HAS_SB) z = z * sc[c + j] + bi[c + j];
        o8[j] = f2bf(z);
    }
    uint4 pk;
    pk.x = (uint32_t)o8[0] | ((uint32_t)o8[1] << 16);
    pk.y = (uint32_t)o8[2] | ((uint32_t)o8[3] << 16);
    pk.z = (uint32_t)o8[4] | ((uint32_t)o8[5] << 16);
    pk.w = (uint32_t)o8[6] | ((uint32_t)o8[7] << 16);
    *reinterpret_cast<uint4*>(out + row * 512 + c) = pk;
}

// ---------- weight transpose-convert: f32 [L][K][N] -> bf16 [L][row0+N][K], opt row-scale ----------
__global__ __launch_bounds__(256)
void wtrans(const float* __restrict__ W, uint16_t* __restrict__ WT, int K, int N,
            size_t lstride, int row0, const float* __restrict__ kscale)
{
    __shared__ float tile[32][33];
    const int l = blockIdx.z;
    const int k0 = blockIdx.x * 32, n0 = blockIdx.y * 32;
    const float* Wl = W + (size_t)l * K * N;
    uint16_t* WTl = WT + (size_t)l * lstride;
    const int tx = threadIdx.x, ty = threadIdx.y;  // (32,8)
#pragma unroll
    for (int j = 0; j < 4; ++j) {
        const int k = k0 + ty + j * 8;
        float w = Wl[(size_t)k * N + n0 + tx];
        if (kscale) w *= kscale[l * K + k];
        tile[ty + j * 8][tx] = w;
    }
    __syncthreads();
#pragma unroll
    for (int j = 0; j < 4; ++j)
        WTl[(size_t)(row0 + n0 + ty + j * 8) * K + k0 + tx] = f2bf(tile[tx][ty + j * 8]);
}

// ---------- bias fold: out[l*1024 + (z?512:0) + n] = sum_k b[l][k] * W[l][k][n] ----------
__global__ __launch_bounds__(256)
void bfold(const float* __restrict__ b, const float* __restrict__ Wq,
           const float* __restrict__ Wk, float* __restrict__ out)
{
    const int n = blockIdx.x * 256 + threadIdx.x;   // grid (2, 6, 2)
    const int l = blockIdx.y, sel = blockIdx.z;
    const float* bb = b + l * 512;
    const float* W = (sel ? Wk : Wq) + (size_t)l * 512 * 512;
    float s = 0.f;
    for (int k = 0; k < 512; ++k) s += bb[k] * W[(size_t)k * 512 + n];
    out[l * 1024 + sel * 512 + n] = s;
}

// ---------- GEMM v8: counted-vmcnt depth-2, 2D-rect XCD swizzle, coalesced epilogues ----------
// C[M,N] = A[M,K] @ BT[N,K]^T. Requires (M/BM)%2==0, (N/BN)%4==0.
// OUT_VT: 1 = all cols scatter to vt[bh][d][n]; 2 = cols >= 1024 scatter, rest normal.
template<int BM, int BN, int NWR, int NWC, int MINW,
         int HAS_BIAS, int HAS_RESID, int DO_GELU, int OUT_BF16, int OUT_VT>
__global__ __launch_bounds__(NWR * NWC * 64, MINW)
void gemm8(const uint16_t* __restrict__ A, const uint16_t* __restrict__ BT,
           const float* __restrict__ bias, const float* __restrict__ resid,
           void* __restrict__ outp, uint16_t* __restrict__ vt,
           int M, int N, int K)
{
    constexpr int NT = NWR * NWC * 64;
    constexpr int WM = BM / NWR, WN = BN / NWC;
    constexpr int FM = WM / 16, FN = WN / 16;
    constexpr int ASLOTS = 8 * BM, BSLOTS = 8 * BN, TOT = ASLOTS + BSLOTS;
    constexpr int S = TOT / NT;
    static_assert(S == 4, "vmcnt literal assumes S==4");
    static_assert(BM * BN <= 2 * ASLOTS * 8, "epilogue LDS reuse needs BN<=128");
    __shared__ uint16_t As[2][ASLOTS * 8];
    __shared__ uint16_t Bs[2][BSLOTS * 8];
    const int tid = threadIdx.x, lane = tid & 63;
    const int w = tid >> 6, wr = w / NWC, wc = w % NWC;
    const int kg = lane >> 4, lr = lane & 15;
    // 2D-rectangle XCD swizzle: each XCD owns an (nbm/2)x(nbn/4) tile rectangle.
    const int nbn = N / BN, nbm = M / BM;
    const int rect_m = nbm >> 1, rect_n = nbn >> 2;
    const int xcd = blockIdx.x & 7, c = blockIdx.x >> 3;
    const int bm = (xcd >> 2) * rect_m + c / rect_n;
    const int bn = (xcd & 3) * rect_n + c % rect_n;
    const size_t m0 = (size_t)bm * BM;
    const size_t n0 = (size_t)bn * BN;

    auto stage = [&](int b, int k0) {
#pragma unroll
        for (int j = 0; j < S; ++j) {
            const int s = j * NT + tid;
            if (s < ASLOTS) {
                const int sub = s / BM, row = s % BM;
                async_lds16(A + (m0 + row) * K + k0 + sub * 8, &As[b][s * 8]);
            } else {
                const int s2 = s - ASLOTS;
                const int sub = s2 / BN, row = s2 % BN;
                async_lds16(BT + (n0 + row) * K + k0 + sub * 8, &Bs[b][s2 * 8]);
            }
        }
    };

    f32x4 acc[FM][FN] = {};
    const int nt = K / 64;
    stage(0, 0);
    stage(1, 64);
    int cur = 0;
    for (int t = 0; t < nt; ++t) {
        if (t < nt - 1) wait_vmcnt<S>(); else wait_vmcnt<0>();
        SBAR;
        s16x8 af[2][FM], bf[2][FN];
#pragma unroll
        for (int ks = 0; ks < 2; ++ks) {
#pragma unroll
            for (int i = 0; i < FM; ++i)
                af[ks][i] = *(const s16x8*)&As[cur][((ks * 4 + kg) * BM + wr * WM + i * 16 + lr) * 8];
#pragma unroll
            for (int j = 0; j < FN; ++j)
                bf[ks][j] = *(const s16x8*)&Bs[cur][((ks * 4 + kg) * BN + wc * WN + j * 16 + lr) * 8];
        }
        __builtin_amdgcn_s_setprio(1);
#pragma unroll
        for (int ks = 0; ks < 2; ++ks)
#pragma unroll
            for (int i = 0; i < FM; ++i)
#pragma unroll
                for (int j = 0; j < FN; ++j)
                    acc[i][j] = mfma16(af[ks][i], bf[ks][j], acc[i][j]);
        __builtin_amdgcn_s_setprio(0);
        LGKM0; SCHED0;
        SBAR;
        if (t + 2 < nt) stage(cur, (t + 2) * 64);
        cur ^= 1;
    }
    // ---- epilogues (LDS reuse is safe: every wave did lgkmcnt(0) before final barrier) ----
    uint16_t* lt = (uint16_t*)As;   // BM*BN bf16 tile buffer
    if (OUT_VT == 1 || (OUT_VT == 2 && n0 >= 1024)) {
        // stage COL-major (transposed) with XOR swizzle, then coalesced writes to vt
#pragma unroll
        for (int i = 0; i < FM; ++i) {
            const int rl0 = wr * WM + i * 16 + kg * 4;
#pragma unroll
            for (int j = 0; j < FN; ++j) {
                const int cl = wc * WN + j * 16 + lr;
                const int gcol = (int)n0 + cl;
                const int c2 = (OUT_VT == 2) ? gcol - 1024 : gcol;
                const float bval = HAS_BIAS ? bias[c2] : 0.0f;
#pragma unroll
                for (int r = 0; r < 4; ++r) {
                    const int rl = rl0 + r;
                    lt[cl * BM + (rl ^ ((cl & 7) << 3))] = f2bf(acc[i][j][r] + bval);
                }
            }
        }
        __syncthreads();
        const int b = (int)(m0 >> 10), nloc = (int)(m0 & 1023);
        constexpr int PER = BM * BN / 8 / NT;
#pragma unroll
        for (int cth = 0; cth < PER; ++cth) {
            const int s = cth * NT + tid;
            const int cl = s / (BM / 8), rc = s % (BM / 8);
            uint4 val = *(const uint4*)&lt[cl * BM + (rc ^ (cl & 7)) * 8];
            const int gcol = (int)n0 + cl;
            const int c2 = (OUT_VT == 2) ? gcol - 1024 : gcol;
            const int h = c2 >> 6, d = c2 & 63;
            *(uint4*)&vt[((size_t)(b * 8 + h) * 64 + d) * 1024 + nloc + rc * 8] = val;
        }
        return;
    }
    if (OUT_BF16) {
        // stage ROW-major with XOR swizzle, then coalesced 16B writes
#pragma unroll
        for (int i = 0; i < FM; ++i) {
            const int rl0 = wr * WM + i * 16 + kg * 4;
#pragma unroll
            for (int j = 0; j < FN; ++j) {
                const int cl = wc * WN + j * 16 + lr;
                const float bval = HAS_BIAS ? bias[n0 + cl] : 0.0f;
#pragma unroll
                for (int r = 0; r < 4; ++r) {
                    const int rl = rl0 + r;
                    float v = acc[i][j][r] + bval;
                    if (DO_GELU) v = gelu_exact(v);
                    lt[rl * BN + (cl ^ ((rl & 7) << 3))] = f2bf(v);
                }
            }
        }
        __syncthreads();
        constexpr int PER = BM * BN / 8 / NT;
#pragma unroll
        for (int cth = 0; cth < PER; ++cth) {
            const int s = cth * NT + tid;
            const int rl = s / (BN / 8), cc = s % (BN / 8);
            uint4 val = *(const uint4*)&lt[rl * BN + (cc ^ (rl & 7)) * 8];
            *(uint4*)&((uint16_t*)outp)[(m0 + rl) * N + n0 + cc * 8] = val;
        }
        return;
    }
    // f32 + residual path (direct stores)
#pragma unroll
    for (int i = 0; i < FM; ++i) {
        const size_t rbase = m0 + wr * WM + i * 16 + kg * 4;
#pragma unroll
        for (int j = 0; j < FN; ++j) {
            const size_t col = n0 + wc * WN + j * 16 + lr;
            const float bval = HAS_BIAS ? bias[col] : 0.0f;
#pragma unroll
            for (int r = 0; r < 4; ++r) {
                const size_t row = rbase + r;
                float v = acc[i][j][r] + bval;
                if (DO_GELU)  v = gelu_exact(v);
                if (HAS_RESID) v += resid[row * (size_t)N + col];
                ((float*)outp)[row * (size_t)N + col] = v;
            }
        }
    }
}

// ---------- flash attention: no-max softmax, fragment-ordered LDS, 1 barrier/tile ----------
__global__ __launch_bounds__(256)
void attn_flash(const uint16_t* __restrict__ Qb, const uint16_t* __restrict__ Kb,
                const uint16_t* __restrict__ Vt, uint16_t* __restrict__ Ob,
                int qstride, int kstride, int qoff, int koff)
{
    __shared__ uint16_t Ks[2][4096];   // [sub=d/8 8][kv 64][8] fragment-ordered
    __shared__ uint16_t Vs[2][4096];   // [sub=kv/8 8][d 64][8] fragment-ordered
    __shared__ uint16_t Pb[4][1024];   // per-wave [sub=kv/8 8][qrow 16][8]
    const int tid = threadIdx.x, lane = tid & 63, w = tid >> 6;
    const int kg = lane >> 4, lr = lane & 15;
    const int bh = blockIdx.y, b = bh >> 3, h = bh & 7;
    const int q0 = blockIdx.x * 64;
    const float CEXP = 0.125f * 1.44269504f;

    s16x8 aq0, aq1;
    {
        const size_t qrow = (size_t)b * 1024 + q0 + w * 16 + lr;
        const uint16_t* qp = Qb + qrow * qstride + qoff + h * 64 + kg * 8;
        aq0 = *(const s16x8*)qp;
        aq1 = *(const s16x8*)(qp + 32);
    }
    const uint16_t* kbase = Kb + (size_t)b * 1024 * kstride + koff + h * 64;
    const uint16_t* vbase = Vt + (size_t)bh * 65536;

    float l_r[4] = {0.f, 0.f, 0.f, 0.f};
    f32x4 acc[4] = {};

    auto stage = [&](int buf, int kv0) {
#pragma unroll
        for (int j = 0; j < 2; ++j) {
            const int s = j * 256 + tid;
            const int sub = s >> 6, row = s & 63;
            async_lds16(kbase + (size_t)(kv0 + row) * kstride + sub * 8, &Ks[buf][s * 8]);
            async_lds16(vbase + (size_t)row * 1024 + kv0 + sub * 8,      &Vs[buf][s * 8]);
        }
    };

    stage(0, 0);
    __syncthreads();
    int cur = 0;
    for (int t = 0; t < 16; ++t) {
        if (t < 15) stage(cur ^ 1, (t + 1) * 64);
        f32x4 s4[4];
        __builtin_amdgcn_s_setprio(1);
#pragma unroll
        for (int ni = 0; ni < 4; ++ni) {
            s16x8 bk0 = *(const s16x8*)&Ks[cur][(kg * 64 + ni * 16 + lr) * 8];
            s16x8 bk1 = *(const s16x8*)&Ks[cur][((4 + kg) * 64 + ni * 16 + lr) * 8];
            f32x4 z = {};
            z = mfma16(aq0, bk0, z);
            z = mfma16(aq1, bk1, z);
            s4[ni] = z;
        }
        __builtin_amdgcn_s_setprio(0);
#pragma unroll
        for (int ni = 0; ni < 4; ++ni) {
            const int slotb = (ni * 2 + (lr >> 3)) * 16 + kg * 4;
#pragma unroll
            for (int r = 0; r < 4; ++r) {
                const float pe = __builtin_amdgcn_exp2f(s4[ni][r] * CEXP);
                l_r[r] += pe;
                Pb[w][(slotb + r) * 8 + (lr & 7)] = f2bf(pe);
            }
        }
        s16x8 ap0 = *(const s16x8*)&Pb[w][(kg * 16 + lr) * 8];
        s16x8 ap1 = *(const s16x8*)&Pb[w][((4 + kg) * 16 + lr) * 8];
        __builtin_amdgcn_s_setprio(1);
#pragma unroll
        for (int ni = 0; ni < 4; ++ni) {
            s16x8 bv0 = *(const s16x8*)&Vs[cur][(kg * 64 + ni * 16 + lr) * 8];
            s16x8 bv1 = *(const s16x8*)&Vs[cur][((4 + kg) * 64 + ni * 16 + lr) * 8];
            acc[ni] = mfma16(ap0, bv0, acc[ni]);
            acc[ni] = mfma16(ap1, bv1, acc[ni]);
        }
        __builtin_amdgcn_s_setprio(0);
        __syncthreads();
        cur ^= 1;
    }
    float linv[4];
#pragma unroll
    for (int r = 0; r < 4; ++r) {
        float l = l_r[r];
        l += __shfl_xor(l, 1); l += __shfl_xor(l, 2);
        l += __shfl_xor(l, 4); l += __shfl_xor(l, 8);
        linv[r] = 1.0f / l;
    }
#pragma unroll
    for (int ni = 0; ni < 4; ++ni)
#pragma unroll
        for (int r = 0; r < 4; ++r) {
            const float v = acc[ni][r] * linv[r];
            const size_t row = (size_t)b * 1024 + q0 + w * 16 + kg * 4 + r;
            Ob[row * 512 + h * 64 + ni * 16 + lr] = f2bf(v);
        }
}

// ---------- host ----------
extern "C" void kernel_launch(void* const* d_in, const int* in_sizes, int n_in,
                              void* d_out, int out_size, void* d_ws, size_t ws_size,
                              hipStream_t stream)
{
    (void)in_sizes; (void)n_in; (void)out_size; (void)ws_size;
    const float* g     = (const float*)d_in[0];
    const float* x0    = (const float*)d_in[1];
    const float* ln1_s = (const float*)d_in[2];
    const float* ln1_b = (const float*)d_in[3];
    const float* Wqkv  = (const float*)d_in[4];
    const float* Wo_sa = (const float*)d_in[5];
    const float* bo_sa = (const float*)d_in[6];
    const float* lng_s = (const float*)d_in[7];
    const float* lng_b = (const float*)d_in[8];
    const float* lnx_s = (const float*)d_in[9];
    const float* lnx_b = (const float*)d_in[10];
    const float* Wq    = (const float*)d_in[11];
    const float* Wk    = (const float*)d_in[12];
    const float* Wv    = (const float*)d_in[13];
    const float* bv    = (const float*)d_in[14];
    const float* Wo_ca = (const float*)d_in[15];
    const float* bo_ca = (const float*)d_in[16];
    const float* lnf_s = (const float*)d_in[17];
    const float* lnf_b = (const float*)d_in[18];
    const float* W1    = (const float*)d_in[19];
    const float* b1    = (const float*)d_in[20];
    const float* W2    = (const float*)d_in[21];
    const float* b2    = (const float*)d_in[22];

    float* x = (float*)d_out;  // running residual stream (f32)

    char* p = (char*)d_ws;
    auto carve = [&](size_t n) { char* r = p; p += (n + 255) & ~(size_t)255; return r; };
    uint16_t* WqkT  = (uint16_t*)carve(6ull * 1024 * 512 * 2);  // scaled [l][WqT|WkT][512]
    uint16_t* WvT   = (uint16_t*)carve(6ull * 512 * 512 * 2);
    uint16_t* WocaT = (uint16_t*)carve(6ull * 512 * 512 * 2);
    uint16_t* WqkvT = (uint16_t*)carve(6ull * 1536 * 512 * 2);
    uint16_t* WosaT = (uint16_t*)carve(6ull * 512 * 512 * 2);
    uint16_t* W1T   = (uint16_t*)carve(6ull * 2048 * 512 * 2);
    uint16_t* W2T   = (uint16_t*)carve(6ull * 512 * 2048 * 2);
    float*    bqk   = (float*)carve(6144ull * 4);               // folded LN-bias @ W
    uint16_t* zg    = (uint16_t*)carve(4096ull * 512 * 2);      // standardized g
    uint16_t* qkall = (uint16_t*)carve(4096ull * 6144 * 2);     // all layers' Q|K
    uint16_t* xn    = (uint16_t*)carve(4096ull * 512 * 2);
    uint16_t* qkvu  = (uint16_t*)carve(4096ull * 1536 * 2);
    uint16_t* vt    = (uint16_t*)carve(32ull * 64 * 1024 * 2);
    uint16_t* ab    = (uint16_t*)carve(4096ull * 512 * 2);
    uint16_t* hb    = (uint16_t*)carve(4096ull * 2048 * 2);

    // ---- prep: weights (QK scale-folded), bias fold ----
    dim3 tb(32, 8);
    wtrans<<<dim3(16, 16, 6), tb, 0, stream>>>(Wq,    WqkT,  512, 512,  1024ull * 512, 0,   lng_s);
    wtrans<<<dim3(16, 16, 6), tb, 0, stream>>>(Wk,    WqkT,  512, 512,  1024ull * 512, 512, lng_s);
    wtrans<<<dim3(16, 16, 6), tb, 0, stream>>>(Wv,    WvT,   512, 512,  512ull * 512, 0, nullptr);
    wtrans<<<dim3(16, 16, 6), tb, 0, stream>>>(Wo_ca, WocaT, 512, 512,  512ull * 512, 0, nullptr);
    wtrans<<<dim3(16, 48, 6), tb, 0, stream>>>(Wqkv,  WqkvT, 512, 1536, 1536ull * 512, 0, nullptr);
    wtrans<<<dim3(16, 16, 6), tb, 0, stream>>>(Wo_sa, WosaT, 512, 512,  512ull * 512, 0, nullptr);
    wtrans<<<dim3(16, 64, 6), tb, 0, stream>>>(W1,    W1T,   512, 2048, 2048ull * 512, 0, nullptr);
    wtrans<<<dim3(64, 16, 6), tb, 0, stream>>>(W2,    W2T,   2048, 512, 2048ull * 512, 0, nullptr);
    bfold<<<dim3(2, 6, 2), 256, 0, stream>>>(lng_b, Wq, Wk, bqk);

    hipMemcpyAsync(x, x0, 4096ull * 512 * 4, hipMemcpyDeviceToDevice, stream);

    // ---- hoisted Q/K for all layers: qkall = z(g) @ WqkT + bqk ----
    ln_t<0><<<1024, 256, 0, stream>>>(g, nullptr, nullptr, zg);
    ln_t<1><<<1024, 256, 0, stream>>>(x, lnx_s, lnx_b, xn);   // lnx layer 0
    gemm8<128, 128, 2, 4, 4, 1, 0, 0, 1, 0><<<1536, 512, 0, stream>>>(
        zg, WqkT, bqk, nullptr, qkall, nullptr, 4096, 6144, 512);

    const dim3 ga(16, 32);

    for (int l = 0; l < 6; ++l) {
        const size_t o512 = (size_t)l * 512, oW = (size_t)l * 512 * 512;
        const size_t oW1 = (size_t)l * 2048 * 512, oWqkv = (size_t)l * 1536 * 512;
        const size_t o2048 = (size_t)l * 2048;

        // ---- relational cross attention (Q,K precomputed) ----
        gemm8<64, 64, 2, 2, 4, 1, 0, 0, 0, 1><<<512, 256, 0, stream>>>(
            xn, WvT + oW, bv + o512, nullptr, nullptr, vt, 4096, 512, 512);
        attn_flash<<<ga, 256, 0, stream>>>(qkall, qkall, vt, ab, 6144, 6144,
                                           l * 1024, l * 1024 + 512);
        gemm8<64, 64, 2, 2, 4, 1, 1, 0, 0, 0><<<512, 256, 0, stream>>>(
            ab, WocaT + oW, bo_ca + o512, x, x, nullptr, 4096, 512, 512);

        // ---- feed-forward 1 ----
        ln_t<1><<<1024, 256, 0, stream>>>(x, lnf_s + o512, lnf_b + o512, xn);
        gemm8<128, 128, 2, 4, 4, 1, 0, 1, 1, 0><<<512, 512, 0, stream>>>(
            xn, W1T + oW1, b1 + o2048, nullptr, hb, nullptr, 4096, 2048, 512);
        gemm8<64, 64, 2, 2, 4, 1, 1, 0, 0, 0><<<512, 256, 0, stream>>>(
            hb, W2T + oW1, b2 + o512, x, x, nullptr, 4096, 512, 2048);
        ln_t<1><<<1024, 256, 0, stream>>>(x, ln1_s + o512, ln1_b + o512, xn);

        // ---- pre-norm self attention ----
        gemm8<128, 128, 2, 4, 4, 0, 0, 0, 1, 2><<<384, 512, 0, stream>>>(
            xn, WqkvT + oWqkv, nullptr, nullptr, qkvu, vt, 4096, 1536, 512);
        attn_flash<<<ga, 256, 0, stream>>>(qkvu, qkvu, vt, ab, 1536, 1536, 0, 512);
        gemm8<64, 64, 2, 2, 4, 1, 1, 0, 0, 0><<<512, 256, 0, stream>>>(
            ab, WosaT + oW, bo_sa + o512, x, x, nullptr, 4096, 512, 512);

        // ---- feed-forward 2 ----
        ln_t<1><<<1024, 256, 0, stream>>>(x, lnf_s + o512, lnf_b + o512, xn);
        gemm8<128, 128, 2, 4, 4, 1, 0, 1, 1, 0><<<512, 512, 0, stream>>>(
            xn, W1T + oW1, b1 + o2048, nullptr, hb, nullptr, 4096, 2048, 512);
        gemm8<64, 64, 2, 2, 4, 1, 1, 0, 0, 0><<<512, 256, 0, stream>>>(
            hb, W2T + oW1, b2 + o512, x, x, nullptr, 4096, 512, 2048);
        if (l < 5)
            ln_t<1><<<1024, 256, 0, stream>>>(x, lnx_s + o512 + 512, lnx_b + o512 + 512, xn);
    }
}